// Round 10
// baseline (481.090 us; speedup 1.0000x reference)
//
#include <hip/hip_runtime.h>
#include <hip/hip_bf16.h>
#include <math.h>

#define EPSN 1e-12f

using bf16x8 = __attribute__((ext_vector_type(8))) __bf16;
using f32x4  = __attribute__((ext_vector_type(4))) float;

__device__ __forceinline__ void gload_lds16(const void* g, void* l) {
  __builtin_amdgcn_global_load_lds(
      (const __attribute__((address_space(1))) unsigned int*)g,
      (__attribute__((address_space(3))) unsigned int*)l, 16, 0, 0);
}

// stage a 128x64 bf16 tile (rows row0.., clamped to maxrow) into swizzled LDS
__device__ __forceinline__ void stage128(const __hip_bfloat16* __restrict__ src,
                                         size_t ldk, int row0, int maxrow, int c0,
                                         __bf16* lds, int w, int lane) {
  #pragma unroll
  for (int j = 0; j < 4; ++j) {
    int ci = w * 256 + j * 64 + lane;
    int row = ci >> 3, kc = ci & 7;
    int srcc = kc ^ (row & 7);
    int r = row0 + row; if (r > maxrow) r = maxrow;
    gload_lds16(src + (size_t)r * ldk + c0 + srcc * 8, (char*)lds + (size_t)ci * 16);
  }
}

// 64x64 wave tile: 4x4 fragments, one K=64 chunk from swizzled LDS
__device__ __forceinline__ void compute64(const __bf16* ldsA, const __bf16* ldsB,
                                          int wr, int wc, int l15, int l4,
                                          f32x4 acc[4][4]) {
  #pragma unroll
  for (int ks = 0; ks < 2; ++ks) {
    int chunk = ks * 4 + l4;
    bf16x8 af[4], bv[4];
    #pragma unroll
    for (int mf = 0; mf < 4; ++mf) {
      int row = wr * 64 + mf * 16 + l15;
      af[mf] = *(const bf16x8*)((const char*)ldsA + row * 128 + ((chunk ^ (row & 7)) << 4));
    }
    #pragma unroll
    for (int nf = 0; nf < 4; ++nf) {
      int col = wc * 64 + nf * 16 + l15;
      bv[nf] = *(const bf16x8*)((const char*)ldsB + col * 128 + ((chunk ^ (col & 7)) << 4));
    }
    #pragma unroll
    for (int mf = 0; mf < 4; ++mf)
      #pragma unroll
      for (int nf = 0; nf < 4; ++nf)
        acc[mf][nf] = __builtin_amdgcn_mfma_f32_16x16x32_bf16(af[mf], bv[nf], acc[mf][nf], 0, 0, 0);
  }
}

// ===== transpose [img][640][100] f32 -> [img*100][640] bf16, fused GAP + sumsq
__global__ __launch_bounds__(256) void k_transpose_bf16(
    const float* __restrict__ src, __hip_bfloat16* __restrict__ dst,
    float* __restrict__ gap, float* __restrict__ sumsq) {
  __shared__ float tile[64][101];
  int img = blockIdx.x;
  int ct = blockIdx.y;
  const float* s = src + ((size_t)img * 640 + ct * 64) * 100;
  int t = threadIdx.x;
  #pragma unroll
  for (int i = 0; i < 25; ++i) {
    int j = t + i * 256;
    int c = j / 100, p = j % 100;
    tile[c][p] = s[(size_t)c * 100 + p];
  }
  __syncthreads();
  if (gap != nullptr) {
    int c = t >> 2, part = t & 3;
    float sm = 0.f;
    #pragma unroll
    for (int p = 0; p < 25; ++p) sm += tile[c][part * 25 + p];
    sm += __shfl_xor(sm, 1);
    sm += __shfl_xor(sm, 2);
    if (part == 0) gap[(size_t)img * 640 + ct * 64 + c] = sm * 0.01f;
  }
  if (t < 100) {
    float acc = 0.f;
    #pragma unroll 8
    for (int c = 0; c < 64; ++c) { float v = tile[c][t]; acc = fmaf(v, v, acc); }
    atomicAdd(&sumsq[(size_t)img * 100 + t], acc);
  }
  __hip_bfloat16* d = dst + (size_t)img * 100 * 640 + ct * 64;
  #pragma unroll
  for (int i = 0; i < 25; ++i) {
    int j = t + i * 256;
    int p = j >> 6, c = j & 63;
    d[(size_t)p * 640 + c] = __float2bfloat16(tile[c][p]);
  }
}

// ===== in-place: x = 1/(sqrt(x)+eps) over qsq(30000)+ssq(10000) =====
__global__ void k_finalize_inv(float* __restrict__ sq) {
  int idx = blockIdx.x * 256 + threadIdx.x;
  if (idx < 40000) sq[idx] = 1.f / (sqrtf(sq[idx]) + EPSN);
}

// ===== fused proto + global d2 =====
__global__ __launch_bounds__(256) void k_proto_d2(
    const float* __restrict__ sgap, const float* __restrict__ qg,
    float* __restrict__ glog) {
  __shared__ float proto[640];
  int bn = blockIdx.x; int b = bn / 5, n = bn % 5;
  int t = threadIdx.x;
  for (int c = t; c < 640; c += 256) {
    float s = 0.f;
    #pragma unroll
    for (int k = 0; k < 5; ++k) s += sgap[(size_t)(b * 25 + n * 5 + k) * 640 + c];
    proto[c] = s * 0.2f;
  }
  __syncthreads();
  int w = t >> 6, lane = t & 63;
  for (int q = w; q < 75; q += 4) {
    const float* qrow = qg + (size_t)(b * 75 + q) * 640;
    float s = 0.f;
    for (int c = lane; c < 640; c += 64) { float d = qrow[c] - proto[c]; s = fmaf(d, d, s); }
    #pragma unroll
    for (int off = 32; off >= 1; off >>= 1) s += __shfl_xor(s, off, 64);
    if (lane == 0) glog[(b * 75 + q) * 5 + n] = -s;
  }
}

// ===== build SP f32 + SPa bf16 [b][325][640] =====
__global__ void k_sp_build(const float* __restrict__ spart, float* __restrict__ SP,
                           __hip_bfloat16* __restrict__ SPa) {
  int idx = blockIdx.x * 256 + threadIdx.x;
  if (idx >= 832000) return;
  int b = idx / (325 * 640);
  int r = idx % (325 * 640);
  int node = r / 640, c = r % 640;
  int s = node / 13, p = node % 13;
  float v = spart[(size_t)((b * 25 + s) * 640 + c) * 13 + p];
  SP[idx] = v;
  SPa[idx] = __float2bfloat16(v);
}

// ===== pack W [cin][cout] f32 -> Wt [w][cout][cin] bf16 =====
__global__ __launch_bounds__(256) void k_w_pack(
    const float* __restrict__ Wq, const float* __restrict__ Wk,
    const float* __restrict__ Wv, __hip_bfloat16* __restrict__ Wt) {
  __shared__ float tile[64][65];
  int t = blockIdx.x;           // 0..99
  int w = blockIdx.y;
  const float* W = (w == 0) ? Wq : ((w == 1) ? Wk : Wv);
  int rt = t / 10, ct = t % 10; // rt: cin tile, ct: cout tile
  int tid = threadIdx.x;
  int cc = tid & 63;
  #pragma unroll
  for (int i = 0; i < 16; ++i) {
    int rr = i * 4 + (tid >> 6);
    tile[rr][cc] = W[(size_t)(rt * 64 + rr) * 640 + ct * 64 + cc];
  }
  __syncthreads();
  #pragma unroll
  for (int i = 0; i < 16; ++i) {
    int rr = i * 4 + (tid >> 6);
    Wt[((size_t)w * 640 + ct * 64 + rr) * 640 + rt * 64 + cc] = __float2bfloat16(tile[cc][rr]);
  }
}

// ===== QKV MFMA: [325x640] @ Wt^T -> Qb16/Kb16 bf16 [node][cout], Vt16 [cout][384]
__global__ __launch_bounds__(256) void k_qkv_mfma(
    const __hip_bfloat16* __restrict__ SPa, const __hip_bfloat16* __restrict__ Wt,
    __hip_bfloat16* __restrict__ Qb16, __hip_bfloat16* __restrict__ Kb16,
    __hip_bfloat16* __restrict__ Vt16) {
  __shared__ __align__(16) __bf16 ldsA[128 * 64];
  __shared__ __align__(16) __bf16 ldsB[128 * 64];
  int nt = blockIdx.x, mt = blockIdx.y, z = blockIdx.z;
  int b = z / 3, w3 = z % 3;
  int tid = threadIdx.x;
  int w = tid >> 6, lane = tid & 63;
  int l15 = lane & 15, l4 = lane >> 4;
  int wr = w >> 1, wc = w & 1;
  const __hip_bfloat16* A = SPa + (size_t)b * 325 * 640;
  const __hip_bfloat16* B = Wt + (size_t)w3 * 640 * 640;

  f32x4 acc[4][4];
  #pragma unroll
  for (int i = 0; i < 4; ++i)
    #pragma unroll
    for (int j = 0; j < 4; ++j) acc[i][j] = (f32x4){0.f, 0.f, 0.f, 0.f};

  for (int kt = 0; kt < 10; ++kt) {
    int c0 = kt * 64;
    __syncthreads();
    stage128(A, 640, mt * 128, 324, c0, ldsA, w, lane);
    stage128(B, 640, nt * 128, 639, c0, ldsB, w, lane);
    __syncthreads();
    compute64(ldsA, ldsB, wr, wc, l15, l4, acc);
  }
  __hip_bfloat16* Qo = Qb16 + (size_t)b * 208000;
  __hip_bfloat16* Ko = Kb16 + (size_t)b * 208000;
  __hip_bfloat16* Vo = Vt16 + (size_t)b * 245760;
  #pragma unroll
  for (int mf = 0; mf < 4; ++mf)
    #pragma unroll
    for (int r = 0; r < 4; ++r) {
      int row = mt * 128 + wr * 64 + mf * 16 + l4 * 4 + r;
      if (row >= 325) continue;
      #pragma unroll
      for (int nf = 0; nf < 4; ++nf) {
        int col = nt * 128 + wc * 64 + nf * 16 + l15;
        float v = acc[mf][nf][r];
        if (w3 == 0)      Qo[(size_t)row * 640 + col] = __float2bfloat16(v);
        else if (w3 == 1) Ko[(size_t)row * 640 + col] = __float2bfloat16(v);
        else              Vo[(size_t)col * 384 + row] = __float2bfloat16(v);
      }
    }
}

// ===== scores MFMA: S[b][325][325] f32 = (Q@K^T)/sqrt(640) =====
__global__ __launch_bounds__(256) void k_scores_mfma(
    const __hip_bfloat16* __restrict__ Qb16, const __hip_bfloat16* __restrict__ Kb16,
    float* __restrict__ S) {
  __shared__ __align__(16) __bf16 ldsA[128 * 64];
  __shared__ __align__(16) __bf16 ldsB[128 * 64];
  const float SCALE = 0.03952847075210474f;
  int nt = blockIdx.x, mt = blockIdx.y, b = blockIdx.z;
  int tid = threadIdx.x;
  int w = tid >> 6, lane = tid & 63;
  int l15 = lane & 15, l4 = lane >> 4;
  int wr = w >> 1, wc = w & 1;
  const __hip_bfloat16* A = Qb16 + (size_t)b * 208000;
  const __hip_bfloat16* B = Kb16 + (size_t)b * 208000;
  f32x4 acc[4][4];
  #pragma unroll
  for (int i = 0; i < 4; ++i)
    #pragma unroll
    for (int j = 0; j < 4; ++j) acc[i][j] = (f32x4){0.f, 0.f, 0.f, 0.f};
  for (int kt = 0; kt < 10; ++kt) {
    int c0 = kt * 64;
    __syncthreads();
    stage128(A, 640, mt * 128, 324, c0, ldsA, w, lane);
    stage128(B, 640, nt * 128, 324, c0, ldsB, w, lane);
    __syncthreads();
    compute64(ldsA, ldsB, wr, wc, l15, l4, acc);
  }
  float* So = S + (size_t)b * 105625;
  #pragma unroll
  for (int mf = 0; mf < 4; ++mf)
    #pragma unroll
    for (int r = 0; r < 4; ++r) {
      int row = mt * 128 + wr * 64 + mf * 16 + l4 * 4 + r;
      if (row >= 325) continue;
      #pragma unroll
      for (int nf = 0; nf < 4; ++nf) {
        int col = nt * 128 + wc * 64 + nf * 16 + l15;
        if (col < 325) So[(size_t)row * 325 + col] = acc[mf][nf][r] * SCALE;
      }
    }
}

// ===== row softmax over 325 -> attb bf16 [row][384], zero-padded =====
__global__ void k_softmax_attb(const float* __restrict__ S, __hip_bfloat16* __restrict__ attb) {
  int w = blockIdx.x * 4 + (threadIdx.x >> 6);
  int lane = threadIdx.x & 63;
  if (w >= 1300) return;
  const float* row = S + (size_t)w * 325;
  float ev[6];
  float mx = -1e30f;
  #pragma unroll
  for (int j = 0; j < 6; ++j) {
    int c = lane + 64 * j;
    float x = (c < 325) ? row[c] : -1e30f;
    ev[j] = x;
    mx = fmaxf(mx, x);
  }
  #pragma unroll
  for (int off = 32; off >= 1; off >>= 1) mx = fmaxf(mx, __shfl_xor(mx, off, 64));
  float sum = 0.f;
  #pragma unroll
  for (int j = 0; j < 6; ++j) {
    int c = lane + 64 * j;
    if (c < 325) { float e = expf(ev[j] - mx); ev[j] = e; sum += e; }
    else ev[j] = 0.f;
  }
  #pragma unroll
  for (int off = 32; off >= 1; off >>= 1) sum += __shfl_xor(sum, off, 64);
  float rinv = 1.f / sum;
  __hip_bfloat16* o = attb + (size_t)w * 384;
  #pragma unroll
  for (int j = 0; j < 6; ++j) {
    int c = lane + 64 * j;
    o[c] = __float2bfloat16((c < 325) ? ev[j] * rinv : 0.f);
  }
}

// ===== AV MFMA: spo f32 [node][640] = attb @ Vt^T + SP =====
__global__ __launch_bounds__(256) void k_av_mfma(
    const __hip_bfloat16* __restrict__ attb, const __hip_bfloat16* __restrict__ Vt16,
    const float* __restrict__ SP, float* __restrict__ spo) {
  __shared__ __align__(16) __bf16 ldsA[128 * 64];
  __shared__ __align__(16) __bf16 ldsB[128 * 64];
  int nt = blockIdx.x, mt = blockIdx.y, b = blockIdx.z;
  int tid = threadIdx.x;
  int w = tid >> 6, lane = tid & 63;
  int l15 = lane & 15, l4 = lane >> 4;
  int wr = w >> 1, wc = w & 1;
  const __hip_bfloat16* A = attb + (size_t)b * 325 * 384;
  const __hip_bfloat16* B = Vt16 + (size_t)b * 245760;
  f32x4 acc[4][4];
  #pragma unroll
  for (int i = 0; i < 4; ++i)
    #pragma unroll
    for (int j = 0; j < 4; ++j) acc[i][j] = (f32x4){0.f, 0.f, 0.f, 0.f};
  for (int kt = 0; kt < 6; ++kt) {
    int c0 = kt * 64;
    __syncthreads();
    stage128(A, 384, mt * 128, 324, c0, ldsA, w, lane);
    stage128(B, 384, nt * 128, 639, c0, ldsB, w, lane);
    __syncthreads();
    compute64(ldsA, ldsB, wr, wc, l15, l4, acc);
  }
  #pragma unroll
  for (int mf = 0; mf < 4; ++mf)
    #pragma unroll
    for (int r = 0; r < 4; ++r) {
      int row = mt * 128 + wr * 64 + mf * 16 + l4 * 4 + r;
      if (row >= 325) continue;
      #pragma unroll
      for (int nf = 0; nf < 4; ++nf) {
        int col = nt * 128 + wc * 64 + nf * 16 + l15;
        size_t idx = ((size_t)b * 325 + row) * 640 + col;
        spo[idx] = acc[mf][nf][r] + SP[idx];
      }
    }
}

// ===== pack spo -> normalized bf16 Spn[b][325][640] =====
__global__ __launch_bounds__(256) void k_pack_sp(
    const float* __restrict__ spo, __hip_bfloat16* __restrict__ Spn) {
  __shared__ float red[4];
  __shared__ float s_inv;
  int node = blockIdx.x;
  const float* row = spo + (size_t)node * 640;
  int t = threadIdx.x;
  float s = 0.f;
  for (int e = t; e < 640; e += 256) { float v = row[e]; s = fmaf(v, v, s); }
  #pragma unroll
  for (int off = 32; off >= 1; off >>= 1) s += __shfl_xor(s, off, 64);
  if ((t & 63) == 0) red[t >> 6] = s;
  __syncthreads();
  if (t == 0) s_inv = 1.f / (sqrtf(red[0] + red[1] + red[2] + red[3]) + EPSN);
  __syncthreads();
  float inv = s_inv;
  for (int e = t; e < 640; e += 256)
    Spn[(size_t)node * 640 + e] = __float2bfloat16(row[e] * inv);
}

// ===== pack qpart -> normalized bf16 Qpb[b][975][640] =====
__global__ __launch_bounds__(256) void k_pack_qp(
    const float* __restrict__ qpart, __hip_bfloat16* __restrict__ Qpb) {
  __shared__ float lds0[8320];
  __shared__ float pinv[13];
  int bq = blockIdx.x;
  const float* src = qpart + (size_t)bq * 8320;
  int t = threadIdx.x;
  #pragma unroll
  for (int i = 0; i < 33; ++i) {
    int e = t + i * 256;
    if (e < 8320) lds0[e] = src[e];
  }
  __syncthreads();
  int g = t >> 4, l = t & 15;
  if (g < 13) {
    float s = 0.f;
    for (int c = l; c < 640; c += 16) { float v = lds0[c * 13 + g]; s = fmaf(v, v, s); }
    #pragma unroll
    for (int off = 8; off >= 1; off >>= 1) s += __shfl_xor(s, off, 16);
    if (l == 0) pinv[g] = 1.f / (sqrtf(s) + EPSN);
  }
  __syncthreads();
  #pragma unroll
  for (int i = 0; i < 33; ++i) {
    int j = t + i * 256;
    if (j < 8320) {
      int p = j / 640, c = j % 640;
      Qpb[((size_t)bq * 13 + p) * 640 + c] = __float2bfloat16(lds0[c * 13 + p] * pinv[p]);
    }
  }
}

// ===== part GEMM: Cpart[b][1024][384] = Qpb x Spn^T =====
__global__ __launch_bounds__(256) void k_part_mfma(
    const __hip_bfloat16* __restrict__ Qpb, const __hip_bfloat16* __restrict__ Spn,
    float* __restrict__ Cpart) {
  __shared__ __align__(16) __bf16 ldsA[128 * 64];
  __shared__ __align__(16) __bf16 ldsB[128 * 64];
  int nt = blockIdx.x, mt = blockIdx.y, b = blockIdx.z;
  int tid = threadIdx.x;
  int w = tid >> 6, lane = tid & 63;
  int l15 = lane & 15, l4 = lane >> 4;
  int wr = w >> 1, wc = w & 1;
  const __hip_bfloat16* A = Qpb + (size_t)b * 975 * 640;
  const __hip_bfloat16* B = Spn + (size_t)b * 325 * 640;
  f32x4 acc[4][4];
  #pragma unroll
  for (int i = 0; i < 4; ++i)
    #pragma unroll
    for (int j = 0; j < 4; ++j) acc[i][j] = (f32x4){0.f, 0.f, 0.f, 0.f};
  for (int kt = 0; kt < 10; ++kt) {
    int c0 = kt * 64;
    __syncthreads();
    stage128(A, 640, mt * 128, 974, c0, ldsA, w, lane);
    stage128(B, 640, nt * 128, 324, c0, ldsB, w, lane);
    __syncthreads();
    compute64(ldsA, ldsB, wr, wc, l15, l4, acc);
  }
  #pragma unroll
  for (int mf = 0; mf < 4; ++mf)
    #pragma unroll
    for (int r = 0; r < 4; ++r) {
      int row = mt * 128 + wr * 64 + mf * 16 + l4 * 4 + r;
      #pragma unroll
      for (int nf = 0; nf < 4; ++nf) {
        int col = nt * 128 + wc * 64 + nf * 16 + l15;
        Cpart[((size_t)b * 1024 + row) * 384 + col] = acc[mf][nf][r];
      }
    }
}

// ===== part reduce =====
__global__ void k_part_reduce(const float* __restrict__ Cpart, float* __restrict__ plog) {
  int w = blockIdx.x * 4 + (threadIdx.x >> 6);
  int lane = threadIdx.x & 63;
  if (w >= 1500) return;
  int bq = w / 5, n = w % 5;
  int b = bq / 75, q = bq % 75;
  int qp = lane >> 2, c4 = lane & 3;
  float m = -1e30f;
  if (qp < 13) {
    const float* row = Cpart + ((size_t)b * 1024 + q * 13 + qp) * 384 + n * 65;
    int hi = c4 * 17 + 17; if (hi > 65) hi = 65;
    for (int cc = c4 * 17; cc < hi; ++cc) m = fmaxf(m, row[cc]);
  }
  m = fmaxf(m, __shfl_xor(m, 1));
  m = fmaxf(m, __shfl_xor(m, 2));
  float contrib = (qp < 13 && c4 == 0) ? m : 0.f;
  #pragma unroll
  for (int off = 32; off >= 1; off >>= 1) contrib += __shfl_xor(contrib, off, 64);
  if (lane == 0) plog[w] = contrib;
}

// ===== pixel GEMM bf16 MFMA, 64x64 wave tiles, fused strip-max =====
// smax aliased into ldsA (dead after K-loop) -> LDS stays 32768 B = 5 blocks/CU
__global__ __launch_bounds__(256) void k_pixel_mfma(
    const __hip_bfloat16* __restrict__ Qn, const __hip_bfloat16* __restrict__ Sn,
    const float* __restrict__ qinv, const float* __restrict__ sinv,
    float* __restrict__ pmax) {
  __shared__ __align__(16) __bf16 ldsA[128 * 64];
  __shared__ __align__(16) __bf16 ldsB[128 * 64];
  int x = blockIdx.x;
  int strip = x / 5, n = x % 5;
  int qt = blockIdx.y;
  int b = blockIdx.z;
  int tid = threadIdx.x;
  int w = tid >> 6, lane = tid & 63;
  int l15 = lane & 15, l4 = lane >> 4;
  int wr = w >> 1, wc = w & 1;

  const __hip_bfloat16* QnB = Qn + (size_t)b * 7500 * 640;
  const __hip_bfloat16* SnB = Sn + ((size_t)b * 2500 + n * 500) * 640;

  f32x4 acc[4][4];
  #pragma unroll
  for (int i = 0; i < 4; ++i)
    #pragma unroll
    for (int j = 0; j < 4; ++j) acc[i][j] = (f32x4){0.f, 0.f, 0.f, 0.f};

  for (int kt = 0; kt < 10; ++kt) {
    int c0 = kt * 64;
    __syncthreads();
    stage128(QnB, 640, qt * 128, 7499, c0, ldsA, w, lane);
    stage128(SnB, 640, strip * 128, 499, c0, ldsB, w, lane);
    __syncthreads();
    compute64(ldsA, ldsB, wr, wc, l15, l4, acc);
  }

  int z = b * 5 + n;
  float sscale[4]; bool svalid[4];
  #pragma unroll
  for (int nf = 0; nf < 4; ++nf) {
    int scol = strip * 128 + wc * 64 + nf * 16 + l15;
    svalid[nf] = scol < 500;
    sscale[nf] = sinv[b * 2500 + n * 500 + (svalid[nf] ? scol : 0)];
  }
  // reuse ldsA as the cross-wave max buffer (dead after K-loop)
  float* smax = (float*)ldsA;   // [128][2]
  __syncthreads();              // all waves done reading ldsA/ldsB
  #pragma unroll
  for (int mf = 0; mf < 4; ++mf) {
    #pragma unroll
    for (int r = 0; r < 4; ++r) {
      float m = -1e30f;
      #pragma unroll
      for (int nf = 0; nf < 4; ++nf) {
        float v = acc[mf][nf][r] * sscale[nf];
        if (svalid[nf]) m = fmaxf(m, v);
      }
      #pragma unroll
      for (int off = 8; off >= 1; off >>= 1) m = fmaxf(m, __shfl_xor(m, off));
      if (l15 == 0) smax[(wr * 64 + mf * 16 + l4 * 4 + r) * 2 + wc] = m;
    }
  }
  __syncthreads();
  if (tid < 128) {
    int row = qt * 128 + tid;
    if (row < 7500) {
      float m = fmaxf(smax[tid * 2], smax[tid * 2 + 1]);
      pmax[((size_t)z * 7500 + row) * 4 + strip] = m * qinv[b * 7500 + row];
    }
  }
}

// ===== pixel reduce (wave-parallel) =====
__global__ void k_pixel_reduce(const float* __restrict__ pmax, float* __restrict__ pxlog) {
  int t = blockIdx.x * 4 + (threadIdx.x >> 6);
  int lane = threadIdx.x & 63;
  if (t >= 1500) return;
  int r = t / 5, n = t % 5;
  int b = r / 75, q = r % 75;
  const float* base = pmax + (size_t)((b * 5 + n) * 7500 + q * 100) * 4;
  float s = 0.f;
  for (int p = lane; p < 100; p += 64) {
    float4 v = *(const float4*)&base[p * 4];
    s += fmaxf(fmaxf(v.x, v.y), fmaxf(v.z, v.w));
  }
  #pragma unroll
  for (int off = 32; off >= 1; off >>= 1) s += __shfl_xor(s, off, 64);
  if (lane == 0) pxlog[t] = s;
}

// ===== final combine =====
__device__ inline void softmax5_add(const float* l, float wgt, float* acc) {
  float m = fmaxf(fmaxf(fmaxf(l[0], l[1]), fmaxf(l[2], l[3])), l[4]);
  float e[5]; float s = 0.f;
  #pragma unroll
  for (int i = 0; i < 5; ++i) { e[i] = expf(l[i] - m); s += e[i]; }
  float r = wgt / s;
  #pragma unroll
  for (int i = 0; i < 5; ++i) acc[i] += e[i] * r;
}

__global__ void k_combine(const float* __restrict__ plog, const float* __restrict__ pxlog,
                          const float* __restrict__ glog, float* __restrict__ out) {
  int t = blockIdx.x * blockDim.x + threadIdx.x;
  if (t >= 300) return;
  float accv[5] = {0.f, 0.f, 0.f, 0.f, 0.f};
  float l[5];
  #pragma unroll
  for (int i = 0; i < 5; ++i) l[i] = plog[t * 5 + i];
  softmax5_add(l, 1.0f, accv);
  #pragma unroll
  for (int i = 0; i < 5; ++i) l[i] = pxlog[t * 5 + i];
  softmax5_add(l, 0.5f, accv);
  #pragma unroll
  for (int i = 0; i < 5; ++i) l[i] = glog[t * 5 + i];
  softmax5_add(l, 0.5f, accv);
  #pragma unroll
  for (int i = 0; i < 5; ++i) out[t * 5 + i] = accv[i];
}

// ===== launch =====
extern "C" void kernel_launch(void* const* d_in, const int* in_sizes, int n_in,
                              void* d_out, int out_size, void* d_ws, size_t ws_size,
                              hipStream_t stream) {
  (void)in_sizes; (void)n_in; (void)out_size; (void)ws_size;
  const float* support = (const float*)d_in[0];  // [4,25,640,10,10]
  const float* query   = (const float*)d_in[1];  // [4,75,640,10,10]
  const float* spart   = (const float*)d_in[2];  // [4,25,640,13,1]
  const float* qpart   = (const float*)d_in[3];  // [4,75,640,13,1]
  const float* Wq      = (const float*)d_in[4];
  const float* Wk      = (const float*)d_in[5];
  const float* Wv      = (const float*)d_in[6];
  float* out = (float*)d_out;                    // [300,5]
  float* ws = (float*)d_ws;

  size_t o = 0;
  __hip_bfloat16* Qn  = (__hip_bfloat16*)(ws + o); o += 9600000;  // 4*7500*640
  __hip_bfloat16* Sn  = (__hip_bfloat16*)(ws + o); o += 3200000;  // 4*2500*640
  __hip_bfloat16* Qpb = (__hip_bfloat16*)(ws + o); o += 1248000;  // 4*975*640
  __hip_bfloat16* Spn = (__hip_bfloat16*)(ws + o); o += 416000;   // 4*325*640
  __hip_bfloat16* SPa = (__hip_bfloat16*)(ws + o); o += 416000;   // 4*325*640
  __hip_bfloat16* Wt  = (__hip_bfloat16*)(ws + o); o += 614400;   // 3*640*640
  float* qkv_region = ws + o;                       // reused region:
  __hip_bfloat16* Qb16 = (__hip_bfloat16*)(ws + o); o += 416000;  // 4*325*640
  __hip_bfloat16* Kb16 = (__hip_bfloat16*)(ws + o); o += 416000;  // 4*325*640
  __hip_bfloat16* Vt16 = (__hip_bfloat16*)(ws + o); o += 491520;  // 4*640*384
  __hip_bfloat16* attb = (__hip_bfloat16*)(ws + o); o += 249600;  // 4*325*384
  float* qsq   = ws + o; o += 30000;   // becomes qinv in place
  float* ssq   = ws + o; o += 10000;   // becomes sinv in place
  float* qg    = ws + o; o += 192000;
  float* sgap  = ws + o; o += 64000;
  float* SP    = ws + o; o += 832000;
  float* S     = ws + o; o += 422500;
  float* spo   = ws + o; o += 832000;
  float* plog  = ws + o; o += 1500;
  float* pxlog = ws + o; o += 1500;
  float* glog  = ws + o; o += 1500;
  // aliases (lifetimes disjoint, stream-serialized):
  float* Cpart = qkv_region;   // 4*1024*384 = 1,572,864 <= 1,573,120 (Qb16..attb)
  float* pmax  = qkv_region;   // 600,000 (written after Cpart is consumed)
  float* qinv  = qsq;
  float* sinv  = ssq;

  hipMemsetAsync(qsq, 0, 40000 * sizeof(float), stream);  // qsq+ssq contiguous
  k_transpose_bf16<<<dim3(300, 10), 256, 0, stream>>>(query, Qn, qg, qsq);
  k_transpose_bf16<<<dim3(100, 10), 256, 0, stream>>>(support, Sn, sgap, ssq);
  k_finalize_inv<<<157, 256, 0, stream>>>(qsq);
  k_sp_build<<<3250, 256, 0, stream>>>(spart, SP, SPa);
  k_w_pack<<<dim3(100, 3), 256, 0, stream>>>(Wq, Wk, Wv, Wt);
  k_qkv_mfma<<<dim3(5, 3, 12), 256, 0, stream>>>(SPa, Wt, Qb16, Kb16, Vt16);
  k_scores_mfma<<<dim3(3, 3, 4), 256, 0, stream>>>(Qb16, Kb16, S);
  k_softmax_attb<<<325, 256, 0, stream>>>(S, attb);
  k_av_mfma<<<dim3(5, 3, 4), 256, 0, stream>>>(attb, Vt16, SP, spo);
  k_pack_sp<<<1300, 256, 0, stream>>>(spo, Spn);
  k_pack_qp<<<300, 256, 0, stream>>>(qpart, Qpb);
  k_part_mfma<<<dim3(3, 8, 4), 256, 0, stream>>>(Qpb, Spn, Cpart);
  k_part_reduce<<<375, 256, 0, stream>>>(Cpart, plog);
  k_proto_d2<<<20, 256, 0, stream>>>(sgap, qg, glog);
  k_pixel_mfma<<<dim3(20, 59, 4), 256, 0, stream>>>(Qn, Sn, qinv, sinv, pmax);
  k_pixel_reduce<<<375, 256, 0, stream>>>(pmax, pxlog);
  k_combine<<<1, 512, 0, stream>>>(plog, pxlog, glog, out);
}